// Round 2
// baseline (1244.457 us; speedup 1.0000x reference)
//
#include <hip/hip_runtime.h>
#include <cstdint>
#include <cstddef>

#define D 128
#define H 8
#define DH 16

// ---------------------------------------------------------------------------
// K1: masked mean pool over L tokens + speaker embedding add -> x [N,D]
// block = 256 threads = 2 nodes x 128 dims
__global__ __launch_bounds__(256) void pool_kernel(
    const float* __restrict__ features, const int* __restrict__ mask,
    const int* __restrict__ spk_ids, const float* __restrict__ spk_emb,
    float* __restrict__ x, int N, int L)
{
  int n = blockIdx.x * 2 + (threadIdx.x >> 7);
  if (n >= N) return;
  int d = threadIdx.x & 127;
  const float* f = features + (size_t)n * L * D + d;
  float s = 0.f; int cnt = 0;
  for (int l = 0; l < L; ++l) {
    if (mask[n * L + l]) { s += f[(size_t)l * D]; ++cnt; }
  }
  float denom = (cnt > 0) ? (float)cnt : 1.f;
  x[(size_t)n * D + d] = s / denom + spk_emb[(size_t)spk_ids[n] * D + d];
}

// ---------------------------------------------------------------------------
// K2/K6: fp32 tiled GEMM, tile 128 rows x 128 cols, K=128 in chunks of 32.
// mode 0: C[m] = A @ (m<4 ? W_r[m] : W_q); m<4 -> h_all slice, m==4 -> C4 (q)
// mode 1: out = elu(Xres + A @ W0 + bias)
__global__ __launch_bounds__(256) void gemm_kernel(
    const float* __restrict__ A, const float* __restrict__ W0,
    const float* __restrict__ W1, float* __restrict__ C, float* __restrict__ C4,
    const float* __restrict__ Xres, const float* __restrict__ bias,
    int N, int mode)
{
  __shared__ float AsT[32][129];  // [k][row], padded (write-conflict ~2-way)
  __shared__ float Bs[32][128];   // [k][col]
  int t = threadIdx.x;
  int tx = t & 15, ty = t >> 4;
  int row0 = blockIdx.x * 128;
  int m = blockIdx.y;
  const float* B = (m < 4) ? (W0 + (size_t)m * D * D) : W1;
  float* Cm;
  if (mode == 0) Cm = (m < 4) ? (C + (size_t)m * N * D) : C4;
  else Cm = C;

  float acc[8][8];
  #pragma unroll
  for (int i = 0; i < 8; ++i)
    #pragma unroll
    for (int j = 0; j < 8; ++j) acc[i][j] = 0.f;

  for (int kc = 0; kc < D; kc += 32) {
    int kq = t & 7, rbase = t >> 3;
    #pragma unroll
    for (int it = 0; it < 4; ++it) {
      int r = rbase + it * 32;
      int gr = row0 + r;
      float4 v = make_float4(0.f, 0.f, 0.f, 0.f);
      if (gr < N) v = *(const float4*)&A[(size_t)gr * D + kc + kq * 4];
      AsT[kq * 4 + 0][r] = v.x; AsT[kq * 4 + 1][r] = v.y;
      AsT[kq * 4 + 2][r] = v.z; AsT[kq * 4 + 3][r] = v.w;
    }
    int cq = t & 31, kb = t >> 5;
    #pragma unroll
    for (int it = 0; it < 4; ++it) {
      int kk = kb + it * 8;
      *(float4*)&Bs[kk][cq * 4] = *(const float4*)&B[(size_t)(kc + kk) * D + cq * 4];
    }
    __syncthreads();
    #pragma unroll
    for (int kk = 0; kk < 32; ++kk) {
      float a[8], b[8];
      #pragma unroll
      for (int i = 0; i < 8; ++i) a[i] = AsT[kk][ty * 8 + i];
      #pragma unroll
      for (int j = 0; j < 8; ++j) b[j] = Bs[kk][tx * 8 + j];
      #pragma unroll
      for (int i = 0; i < 8; ++i)
        #pragma unroll
        for (int j = 0; j < 8; ++j)
          acc[i][j] = fmaf(a[i], b[j], acc[i][j]);
    }
    __syncthreads();
  }

  if (mode == 0) {
    #pragma unroll
    for (int i = 0; i < 8; ++i) {
      int gr = row0 + ty * 8 + i;
      if (gr >= N) continue;
      float4 v0 = make_float4(acc[i][0], acc[i][1], acc[i][2], acc[i][3]);
      float4 v1 = make_float4(acc[i][4], acc[i][5], acc[i][6], acc[i][7]);
      *(float4*)&Cm[(size_t)gr * D + tx * 8] = v0;
      *(float4*)&Cm[(size_t)gr * D + tx * 8 + 4] = v1;
    }
  } else {
    float bj[8];
    #pragma unroll
    for (int j = 0; j < 8; ++j) bj[j] = bias[tx * 8 + j];
    #pragma unroll
    for (int i = 0; i < 8; ++i) {
      int gr = row0 + ty * 8 + i;
      if (gr >= N) continue;
      const float4* xr = (const float4*)&Xres[(size_t)gr * D + tx * 8];
      float4 x0 = xr[0], x1 = xr[1];
      float vv[8] = {acc[i][0] + x0.x, acc[i][1] + x0.y, acc[i][2] + x0.z, acc[i][3] + x0.w,
                     acc[i][4] + x1.x, acc[i][5] + x1.y, acc[i][6] + x1.z, acc[i][7] + x1.w};
      float ov[8];
      #pragma unroll
      for (int j = 0; j < 8; ++j) {
        float v = vv[j] + bj[j];
        ov[j] = v > 0.f ? v : expm1f(v);   // ELU
      }
      *(float4*)&Cm[(size_t)gr * D + tx * 8]     = make_float4(ov[0], ov[1], ov[2], ov[3]);
      *(float4*)&Cm[(size_t)gr * D + tx * 8 + 4] = make_float4(ov[4], ov[5], ov[6], ov[7]);
    }
  }
}

// ---------------------------------------------------------------------------
// K3: per-(m,n,h) head projections: s_src[r,n,h] = h_r[r,n,h,:].a_src[h]
//     and s_dst[n,h] (m==4) = q[n,h,:].a_dst[h]. s_all layout [5][N][H].
__global__ void score_proj_kernel(
    const float* __restrict__ h_all, const float* __restrict__ q_buf,
    const float* __restrict__ a_src, const float* __restrict__ a_dst,
    float* __restrict__ s_all, int N)
{
  int m = blockIdx.y;
  int idx = blockIdx.x * blockDim.x + threadIdx.x;  // over N*H
  if (idx >= N * H) return;
  int h = idx & 7, n = idx >> 3;
  const float* hv = (m < 4) ? (h_all + ((size_t)m * N + n) * D + h * DH)
                            : (q_buf + (size_t)n * D + h * DH);
  const float* av = ((m < 4) ? a_src : a_dst) + h * DH;
  const float4* hv4 = (const float4*)hv;
  const float4* av4 = (const float4*)av;
  float s = 0.f;
  #pragma unroll
  for (int u = 0; u < 4; ++u) {
    float4 a = hv4[u], b = av4[u];
    s += a.x * b.x + a.y * b.y + a.z * b.z + a.w * b.w;
  }
  s_all[(size_t)m * N * H + idx] = s;
}

// ---------------------------------------------------------------------------
// CSR build
__global__ void hist_kernel(const int* __restrict__ tgt, int* __restrict__ counts, int E)
{
  int e = blockIdx.x * blockDim.x + threadIdx.x;
  if (e < E) atomicAdd(&counts[tgt[e]], 1);
}

__global__ __launch_bounds__(1024) void scan_kernel(
    const int* __restrict__ counts, int* __restrict__ row_start, int N)
{
  __shared__ int sums[1024];
  int t = threadIdx.x;
  int chunk = (N + 1023) >> 10;
  int lo = t * chunk, hi = lo + chunk;
  if (lo > N) lo = N;
  if (hi > N) hi = N;
  int s = 0;
  for (int i = lo; i < hi; ++i) s += counts[i];
  sums[t] = s;
  __syncthreads();
  for (int dlt = 1; dlt < 1024; dlt <<= 1) {
    int v = (t >= dlt) ? sums[t - dlt] : 0;
    __syncthreads();
    sums[t] += v;
    __syncthreads();
  }
  int run = (t == 0) ? 0 : sums[t - 1];
  for (int i = lo; i < hi; ++i) { row_start[i] = run; run += counts[i]; }
  if (t == 1023) row_start[N] = run;
}

__global__ void scatter_kernel(
    const int* __restrict__ src, const int* __restrict__ tgt,
    const int* __restrict__ rel, const int* __restrict__ row_start,
    int* __restrict__ cursor, unsigned* __restrict__ edge_list, int E)
{
  int e = blockIdx.x * blockDim.x + threadIdx.x;
  if (e >= E) return;
  int tg = tgt[e];
  int pos = atomicAdd(&cursor[tg], 1);
  edge_list[row_start[tg] + pos] = (unsigned)src[e] | ((unsigned)rel[e] << 28);
}

// ---------------------------------------------------------------------------
// K5: fused segment-softmax + weighted aggregation. One wave per target node.
// Scores are recomputed from s_all each pass (cheap 32B gathers) -> no degree
// cap, no atomics, single 512B msg gather per edge in the final pass.
__global__ __launch_bounds__(64) void attn_agg_kernel(
    const unsigned* __restrict__ edge_list, const int* __restrict__ row_start,
    const float* __restrict__ s_all, const float* __restrict__ h_all,
    float* __restrict__ agg, int N)
{
  int n = blockIdx.x;
  int lane = threadIdx.x;
  int rs = row_start[n], deg = row_start[n + 1] - rs;
  int d0 = lane * 2;
  if (deg == 0) {
    *(float2*)&agg[(size_t)n * D + d0] = make_float2(0.f, 0.f);
    return;
  }
  const float* s_dst_n = s_all + ((size_t)4 * N + n) * H;
  int hA = lane & 7;               // head handled in passes A/B (i%8 == lane%8)
  float sdA = s_dst_n[hA];
  int tot = deg * 8;

  // pass A: per-head max
  float mx = -INFINITY;
  for (int i = lane; i < tot; i += 64) {
    unsigned p = edge_list[rs + (i >> 3)];
    int s = p & 0x0FFFFFFF, r = (int)(p >> 28);
    float sc = s_all[((size_t)r * N + s) * H + hA] + sdA;
    sc = sc > 0.f ? sc : 0.2f * sc;     // leaky_relu
    mx = fmaxf(mx, sc);
  }
  #pragma unroll
  for (int k = 8; k < 64; k <<= 1) mx = fmaxf(mx, __shfl_xor(mx, k));

  // pass B: denominator
  float den = 0.f;
  for (int i = lane; i < tot; i += 64) {
    unsigned p = edge_list[rs + (i >> 3)];
    int s = p & 0x0FFFFFFF, r = (int)(p >> 28);
    float sc = s_all[((size_t)r * N + s) * H + hA] + sdA;
    sc = sc > 0.f ? sc : 0.2f * sc;
    den += __expf(sc - mx);
  }
  #pragma unroll
  for (int k = 8; k < 64; k <<= 1) den += __shfl_xor(den, k);

  // redistribute stats: aggregation lane covers dims d0,d0+1 -> head lane>>3
  int hC = lane >> 3;
  float mC = __shfl(mx, hC);
  float dC = __shfl(den, hC);
  float sdC = s_dst_n[hC];
  float inv = 1.f / (dC + 1e-9f);

  // pass C: weighted aggregation (msg gather, 512B/edge coalesced)
  float a0 = 0.f, a1 = 0.f;
  for (int j = 0; j < deg; ++j) {
    unsigned p = edge_list[rs + j];
    int s = p & 0x0FFFFFFF, r = (int)(p >> 28);
    float sc = s_all[((size_t)r * N + s) * H + hC] + sdC;
    sc = sc > 0.f ? sc : 0.2f * sc;
    float w = __expf(sc - mC);
    float2 mv = *(const float2*)&h_all[((size_t)r * N + s) * D + d0];
    a0 = fmaf(w, mv.x, a0);
    a1 = fmaf(w, mv.y, a1);
  }
  *(float2*)&agg[(size_t)n * D + d0] = make_float2(a0 * inv, a1 * inv);
}

// ---------------------------------------------------------------------------
extern "C" void kernel_launch(void* const* d_in, const int* in_sizes, int n_in,
                              void* d_out, int out_size, void* d_ws, size_t ws_size,
                              hipStream_t stream)
{
  const float* features = (const float*)d_in[0];
  const int*   mask     = (const int*)d_in[1];
  const int*   edge_index = (const int*)d_in[2];
  const int*   edge_type  = (const int*)d_in[3];
  const int*   spk_ids    = (const int*)d_in[4];
  const float* spk_emb    = (const float*)d_in[5];
  const float* W_r   = (const float*)d_in[6];
  const float* W_q   = (const float*)d_in[7];
  const float* a_src = (const float*)d_in[8];
  const float* a_dst = (const float*)d_in[9];
  const float* W_out = (const float*)d_in[10];
  const float* b_out = (const float*)d_in[11];

  int N = in_sizes[4];          // speaker_ids
  int E = in_sizes[3];          // edge_type
  int L = in_sizes[1] / N;      // mask is [N,L]

  // workspace carve-up (~192 MB total)
  char* p = (char*)d_ws;
  auto alloc = [&](size_t bytes) {
    char* r = p; p += (bytes + 255) & ~(size_t)255; return r;
  };
  float* x      = (float*)alloc((size_t)N * D * 4);
  float* h_all  = (float*)alloc((size_t)4 * N * D * 4);   // h_r, r=0..3
  float* q_buf  = (float*)alloc((size_t)N * D * 4);       // q (only for s_dst)
  float* s_all  = (float*)alloc((size_t)5 * N * H * 4);   // [0..3]=s_src, [4]=s_dst
  float* agg    = (float*)alloc((size_t)N * D * 4);
  int*   counts = (int*)alloc((size_t)N * 4);
  int*   cursor = (int*)alloc((size_t)N * 4);
  int*   row_start = (int*)alloc((size_t)(N + 1) * 4);
  unsigned* edge_list = (unsigned*)alloc((size_t)E * 4);

  const int* srcv = edge_index;
  const int* tgtv = edge_index + E;

  hipMemsetAsync(counts, 0, (size_t)N * 4, stream);
  hipMemsetAsync(cursor, 0, (size_t)N * 4, stream);

  pool_kernel<<<(N + 1) / 2, 256, 0, stream>>>(features, mask, spk_ids, spk_emb, x, N, L);

  int nb = (N + 127) / 128;
  gemm_kernel<<<dim3(nb, 5), 256, 0, stream>>>(x, W_r, W_q, h_all, q_buf,
                                               nullptr, nullptr, N, 0);

  int sthreads = N * H;
  score_proj_kernel<<<dim3((sthreads + 255) / 256, 5), 256, 0, stream>>>(
      h_all, q_buf, a_src, a_dst, s_all, N);

  hist_kernel<<<(E + 255) / 256, 256, 0, stream>>>(tgtv, counts, E);
  scan_kernel<<<1, 1024, 0, stream>>>(counts, row_start, N);
  scatter_kernel<<<(E + 255) / 256, 256, 0, stream>>>(srcv, tgtv, edge_type,
                                                      row_start, cursor, edge_list, E);

  attn_agg_kernel<<<N, 64, 0, stream>>>(edge_list, row_start, s_all, h_all, agg, N);

  gemm_kernel<<<dim3(nb, 1), 256, 0, stream>>>(agg, W_out, W_out, (float*)d_out,
                                               nullptr, x, b_out, N, 1);
}

// Round 3
// 902.748 us; speedup vs baseline: 1.3785x; 1.3785x over previous
//
#include <hip/hip_runtime.h>
#include <hip/hip_bf16.h>
#include <cstdint>
#include <cstddef>

#define D 128
#define H 8
#define DH 16

typedef __bf16 bf16x8 __attribute__((ext_vector_type(8)));
typedef float f32x4 __attribute__((ext_vector_type(4)));

// ---------------------------------------------------------------------------
// K1: masked mean pool + speaker embedding -> x [N,D] f32 and x_bf [N,D] bf16
__global__ __launch_bounds__(256) void pool_kernel(
    const float* __restrict__ features, const int* __restrict__ mask,
    const int* __restrict__ spk_ids, const float* __restrict__ spk_emb,
    float* __restrict__ x, __hip_bfloat16* __restrict__ x_bf, int N, int L)
{
  int n = blockIdx.x * 2 + (threadIdx.x >> 7);
  if (n >= N) return;
  int d = threadIdx.x & 127;
  const float* f = features + (size_t)n * L * D + d;
  float s = 0.f; int cnt = 0;
  for (int l = 0; l < L; ++l) {
    if (mask[n * L + l]) { s += f[(size_t)l * D]; ++cnt; }
  }
  float denom = (cnt > 0) ? (float)cnt : 1.f;
  float v = s / denom + spk_emb[(size_t)spk_ids[n] * D + d];
  x[(size_t)n * D + d] = v;
  x_bf[(size_t)n * D + d] = __float2bfloat16(v);
}

// ---------------------------------------------------------------------------
// K2: build pre-swizzled bf16 B operands.
// B_sw  [4][36][64][8]: concat cols 0..511 = W_r (r=col>>7), cols 512..551 =
//   score-contraction columns c_m[k, m*8+h] (m<4: W_r·a_src per head, m=4:
//   W_q·a_dst), cols 552..575 zero pad.
// B_sw2 [4][8][64][8]: W_out.
// Fragment layout for mfma_f32_16x16x32_bf16 B: lane l, elem j ->
//   B[k = kc*32 + (l>>4)*8 + j][col = ct*16 + (l&15)]
__global__ void bbuild_kernel(
    const float* __restrict__ W_r, const float* __restrict__ W_q,
    const float* __restrict__ a_src, const float* __restrict__ a_dst,
    const float* __restrict__ W_out,
    __hip_bfloat16* __restrict__ B_sw, __hip_bfloat16* __restrict__ B_sw2)
{
  int idx = blockIdx.x * 256 + threadIdx.x;
  const int NP = 4 * 36 * 64 * 8;
  if (idx < NP) {
    int j = idx & 7, l = (idx >> 3) & 63, t2 = idx >> 9;
    int ctg = t2 % 36, kc = t2 / 36;
    int k = kc * 32 + (l >> 4) * 8 + j;
    int col = ctg * 16 + (l & 15);
    float val = 0.f;
    if (col < 512) {
      int r = col >> 7, d = col & 127;
      val = W_r[((size_t)r * D + k) * D + d];
    } else {
      int c = col - 512;
      if (c < 40) {
        int m = c >> 3, h = c & 7;
        float s = 0.f;
        if (m < 4) {
          #pragma unroll
          for (int u = 0; u < DH; ++u)
            s += W_r[((size_t)m * D + k) * D + h * DH + u] * a_src[h * DH + u];
        } else {
          #pragma unroll
          for (int u = 0; u < DH; ++u)
            s += W_q[(size_t)k * D + h * DH + u] * a_dst[h * DH + u];
        }
        val = s;
      }
    }
    B_sw[idx] = __float2bfloat16(val);
  } else {
    int e = idx - NP;
    if (e >= 4 * 8 * 64 * 8) return;
    int j = e & 7, l = (e >> 3) & 63, t2 = e >> 9;
    int ctg = t2 % 8, kc = t2 / 8;
    int k = kc * 32 + (l >> 4) * 8 + j;
    int col = ctg * 16 + (l & 15);
    B_sw2[e] = __float2bfloat16(W_out[(size_t)k * D + col]);
  }
}

// ---------------------------------------------------------------------------
// K3: projection GEMM [N,128] @ [128,576] bf16 MFMA, LDS-free.
// Block = 256 thr = 4 waves; BM=64 (16 rows/wave); blockIdx.y selects 18 of
// 36 col-tiles. Outputs: cols<512 -> hs bf16 [N][512]; cols 512..551 ->
// s_f32 [N][40] fp32.
__global__ __launch_bounds__(256) void proj_kernel(
    const __hip_bfloat16* __restrict__ x_bf, const __hip_bfloat16* __restrict__ B_sw,
    __hip_bfloat16* __restrict__ hs, float* __restrict__ s_f32, int N)
{
  int w = threadIdx.x >> 6, l = threadIdx.x & 63;
  int lr = l & 15, lk = l >> 4;
  int row0 = blockIdx.x * 64 + w * 16;
  int ct0 = blockIdx.y * 18;
  f32x4 acc[18];
  #pragma unroll
  for (int c = 0; c < 18; ++c) acc[c] = (f32x4)(0.f);
  int ar = row0 + lr; if (ar >= N) ar = N - 1;
  const bf16x8* xrow = (const bf16x8*)&x_bf[(size_t)ar * D];
  #pragma unroll
  for (int kc = 0; kc < 4; ++kc) {
    bf16x8 a = xrow[kc * 4 + lk];
    #pragma unroll
    for (int c = 0; c < 18; ++c) {
      bf16x8 b = *(const bf16x8*)&B_sw[(((size_t)kc * 36 + ct0 + c) * 64 + l) * 8];
      acc[c] = __builtin_amdgcn_mfma_f32_16x16x32_bf16(a, b, acc[c], 0, 0, 0);
    }
  }
  #pragma unroll
  for (int c = 0; c < 18; ++c) {
    int col = (ct0 + c) * 16 + lr;
    #pragma unroll
    for (int j = 0; j < 4; ++j) {
      int row = row0 + lk * 4 + j;
      if (row >= N) continue;
      if (col < 512)      hs[(size_t)row * 512 + col] = __float2bfloat16(acc[c][j]);
      else if (col < 552) s_f32[(size_t)row * 40 + (col - 512)] = acc[c][j];
    }
  }
}

// ---------------------------------------------------------------------------
// CSR build: histogram + hierarchical scan + scatter
__global__ void hist_kernel(const int* __restrict__ tgt, int* __restrict__ counts, int E)
{
  int e = blockIdx.x * blockDim.x + threadIdx.x;
  if (e < E) atomicAdd(&counts[tgt[e]], 1);
}

__global__ __launch_bounds__(256) void scan_a_kernel(
    const int* __restrict__ counts, int* __restrict__ row_start,
    int* __restrict__ blk_sums, int N)
{
  __shared__ int sh[256];
  int b = blockIdx.x, t = threadIdx.x, i = b * 256 + t;
  int v = (i < N) ? counts[i] : 0;
  sh[t] = v; __syncthreads();
  for (int d = 1; d < 256; d <<= 1) {
    int u = (t >= d) ? sh[t - d] : 0;
    __syncthreads();
    sh[t] += u;
    __syncthreads();
  }
  if (i < N) row_start[i] = sh[t] - v;   // exclusive within block
  if (t == 255) blk_sums[b] = sh[255];
}

__global__ __launch_bounds__(256) void scan_b_kernel(
    int* __restrict__ blk_sums, int nb, int* __restrict__ row_start, int N, int E)
{
  __shared__ int sh[256];
  int t = threadIdx.x;
  int v = (t < nb) ? blk_sums[t] : 0;
  sh[t] = v; __syncthreads();
  for (int d = 1; d < 256; d <<= 1) {
    int u = (t >= d) ? sh[t - d] : 0;
    __syncthreads();
    sh[t] += u;
    __syncthreads();
  }
  if (t < nb) blk_sums[t] = sh[t] - v;   // exclusive block offsets
  if (t == 0) row_start[N] = E;
}

__global__ void scan_c_kernel(int* __restrict__ row_start,
                              const int* __restrict__ blk_sums, int N)
{
  int i = blockIdx.x * 256 + threadIdx.x;
  if (i < N) row_start[i] += blk_sums[i >> 8];
}

__global__ void scatter_kernel(
    const int* __restrict__ src, const int* __restrict__ tgt,
    const int* __restrict__ rel, const int* __restrict__ row_start,
    int* __restrict__ cursor, unsigned* __restrict__ edge_list, int E)
{
  int e = blockIdx.x * blockDim.x + threadIdx.x;
  if (e >= E) return;
  int tg = tgt[e];
  int pos = atomicAdd(&cursor[tg], 1);
  edge_list[row_start[tg] + pos] = (unsigned)src[e] | ((unsigned)rel[e] << 28);
}

// ---------------------------------------------------------------------------
// K5: fused segment-softmax + aggregation. One wave per target node.
// hs bf16 gathers (256B/edge in pass C), s_f32 fp32 score gathers (32B).
__global__ __launch_bounds__(64) void attn_agg_kernel(
    const unsigned* __restrict__ edge_list, const int* __restrict__ row_start,
    const float* __restrict__ s_f32, const __hip_bfloat16* __restrict__ hs,
    __hip_bfloat16* __restrict__ agg_bf, int N)
{
  int n = blockIdx.x;
  int lane = threadIdx.x;
  int rs = row_start[n], deg = row_start[n + 1] - rs;
  int d0 = lane * 2;
  if (deg == 0) {
    *(unsigned*)&agg_bf[(size_t)n * D + d0] = 0u;   // bf16 zeros
    return;
  }
  const float* s_dst_n = s_f32 + (size_t)n * 40 + 32;
  int hA = lane & 7;
  float sdA = s_dst_n[hA];
  int tot = deg * 8;

  // pass A: per-head max
  float mx = -INFINITY;
  for (int i = lane; i < tot; i += 64) {
    unsigned p = edge_list[rs + (i >> 3)];
    int s = p & 0x0FFFFFFF, r = (int)(p >> 28);
    float sc = s_f32[(size_t)s * 40 + r * 8 + hA] + sdA;
    sc = sc > 0.f ? sc : 0.2f * sc;     // leaky_relu
    mx = fmaxf(mx, sc);
  }
  #pragma unroll
  for (int k = 8; k < 64; k <<= 1) mx = fmaxf(mx, __shfl_xor(mx, k));

  // pass B: denominator
  float den = 0.f;
  for (int i = lane; i < tot; i += 64) {
    unsigned p = edge_list[rs + (i >> 3)];
    int s = p & 0x0FFFFFFF, r = (int)(p >> 28);
    float sc = s_f32[(size_t)s * 40 + r * 8 + hA] + sdA;
    sc = sc > 0.f ? sc : 0.2f * sc;
    den += __expf(sc - mx);
  }
  #pragma unroll
  for (int k = 8; k < 64; k <<= 1) den += __shfl_xor(den, k);

  // redistribute stats: aggregation lane covers dims d0,d0+1 -> head lane>>3
  int hC = lane >> 3;
  float mC = __shfl(mx, hC);
  float dC = __shfl(den, hC);
  float sdC = s_dst_n[hC];
  float inv = 1.f / (dC + 1e-9f);

  // pass C: weighted aggregation (bf16 msg gather, 256B/edge)
  float a0 = 0.f, a1 = 0.f;
  #pragma unroll 2
  for (int j = 0; j < deg; ++j) {
    unsigned p = edge_list[rs + j];
    int s = p & 0x0FFFFFFF, r = (int)(p >> 28);
    float sc = s_f32[(size_t)s * 40 + r * 8 + hC] + sdC;
    sc = sc > 0.f ? sc : 0.2f * sc;
    float w = __expf(sc - mC);
    __hip_bfloat162 mv = *(const __hip_bfloat162*)&hs[(size_t)s * 512 + r * D + d0];
    a0 = fmaf(w, __bfloat162float(mv.x), a0);
    a1 = fmaf(w, __bfloat162float(mv.y), a1);
  }
  __hip_bfloat162 o;
  o.x = __float2bfloat16(a0 * inv);
  o.y = __float2bfloat16(a1 * inv);
  *(__hip_bfloat162*)&agg_bf[(size_t)n * D + d0] = o;
}

// ---------------------------------------------------------------------------
// K6: output GEMM [N,128]@[128,128] bf16 MFMA + residual + bias + ELU -> f32
__global__ __launch_bounds__(256) void out_kernel(
    const __hip_bfloat16* __restrict__ agg_bf, const __hip_bfloat16* __restrict__ B_sw2,
    const float* __restrict__ xres, const float* __restrict__ bias,
    float* __restrict__ out, int N)
{
  int w = threadIdx.x >> 6, l = threadIdx.x & 63;
  int lr = l & 15, lk = l >> 4;
  int row0 = blockIdx.x * 64 + w * 16;
  f32x4 acc[8];
  #pragma unroll
  for (int c = 0; c < 8; ++c) acc[c] = (f32x4)(0.f);
  int ar = row0 + lr; if (ar >= N) ar = N - 1;
  const bf16x8* arow = (const bf16x8*)&agg_bf[(size_t)ar * D];
  #pragma unroll
  for (int kc = 0; kc < 4; ++kc) {
    bf16x8 a = arow[kc * 4 + lk];
    #pragma unroll
    for (int c = 0; c < 8; ++c) {
      bf16x8 b = *(const bf16x8*)&B_sw2[(((size_t)kc * 8 + c) * 64 + l) * 8];
      acc[c] = __builtin_amdgcn_mfma_f32_16x16x32_bf16(a, b, acc[c], 0, 0, 0);
    }
  }
  #pragma unroll
  for (int c = 0; c < 8; ++c) {
    int col = c * 16 + lr;
    float bj = bias[col];
    #pragma unroll
    for (int j = 0; j < 4; ++j) {
      int row = row0 + lk * 4 + j;
      if (row >= N) continue;
      float v = acc[c][j] + xres[(size_t)row * D + col] + bj;
      out[(size_t)row * D + col] = v > 0.f ? v : expm1f(v);
    }
  }
}

// ---------------------------------------------------------------------------
extern "C" void kernel_launch(void* const* d_in, const int* in_sizes, int n_in,
                              void* d_out, int out_size, void* d_ws, size_t ws_size,
                              hipStream_t stream)
{
  const float* features = (const float*)d_in[0];
  const int*   mask     = (const int*)d_in[1];
  const int*   edge_index = (const int*)d_in[2];
  const int*   edge_type  = (const int*)d_in[3];
  const int*   spk_ids    = (const int*)d_in[4];
  const float* spk_emb    = (const float*)d_in[5];
  const float* W_r   = (const float*)d_in[6];
  const float* W_q   = (const float*)d_in[7];
  const float* a_src = (const float*)d_in[8];
  const float* a_dst = (const float*)d_in[9];
  const float* W_out = (const float*)d_in[10];
  const float* b_out = (const float*)d_in[11];

  int N = in_sizes[4];          // speaker_ids
  int E = in_sizes[3];          // edge_type
  int L = in_sizes[1] / N;      // mask is [N,L]

  char* p = (char*)d_ws;
  auto alloc = [&](size_t bytes) {
    char* r = p; p += (bytes + 255) & ~(size_t)255; return r;
  };
  float*           x      = (float*)alloc((size_t)N * D * 4);
  __hip_bfloat16*  x_bf   = (__hip_bfloat16*)alloc((size_t)N * D * 2);
  __hip_bfloat16*  hs     = (__hip_bfloat16*)alloc((size_t)N * 512 * 2);
  float*           s_f32  = (float*)alloc((size_t)N * 40 * 4);
  __hip_bfloat16*  agg_bf = (__hip_bfloat16*)alloc((size_t)N * D * 2);
  __hip_bfloat16*  B_sw   = (__hip_bfloat16*)alloc((size_t)4 * 36 * 64 * 8 * 2);
  __hip_bfloat16*  B_sw2  = (__hip_bfloat16*)alloc((size_t)4 * 8 * 64 * 8 * 2);
  int*   counts    = (int*)alloc((size_t)N * 4);
  int*   cursor    = (int*)alloc((size_t)N * 4);
  int*   row_start = (int*)alloc((size_t)(N + 1) * 4);
  int*   blk_sums  = (int*)alloc((size_t)256 * 4);
  unsigned* edge_list = (unsigned*)alloc((size_t)E * 4);

  const int* srcv = edge_index;
  const int* tgtv = edge_index + E;

  hipMemsetAsync(counts, 0, (size_t)N * 4, stream);
  hipMemsetAsync(cursor, 0, (size_t)N * 4, stream);

  const int NB_TOT = 4 * 36 * 64 * 8 + 4 * 8 * 64 * 8;
  bbuild_kernel<<<(NB_TOT + 255) / 256, 256, 0, stream>>>(
      W_r, W_q, a_src, a_dst, W_out, B_sw, B_sw2);

  pool_kernel<<<(N + 1) / 2, 256, 0, stream>>>(features, mask, spk_ids, spk_emb,
                                               x, x_bf, N, L);

  int nbm = (N + 63) / 64;
  proj_kernel<<<dim3(nbm, 2), 256, 0, stream>>>(x_bf, B_sw, hs, s_f32, N);

  hist_kernel<<<(E + 255) / 256, 256, 0, stream>>>(tgtv, counts, E);
  int nb_scan = (N + 255) / 256;
  scan_a_kernel<<<nb_scan, 256, 0, stream>>>(counts, row_start, blk_sums, N);
  scan_b_kernel<<<1, 256, 0, stream>>>(blk_sums, nb_scan, row_start, N, E);
  scan_c_kernel<<<nb_scan, 256, 0, stream>>>(row_start, blk_sums, N);
  scatter_kernel<<<(E + 255) / 256, 256, 0, stream>>>(srcv, tgtv, edge_type,
                                                      row_start, cursor, edge_list, E);

  attn_agg_kernel<<<N, 64, 0, stream>>>(edge_list, row_start, s_f32, hs, agg_bf, N);

  out_kernel<<<nbm, 256, 0, stream>>>(agg_bf, B_sw2, x, b_out, (float*)d_out, N);
}